// Round 5
// baseline (372.007 us; speedup 1.0000x reference)
//
#include <hip/hip_runtime.h>
#include <cstdint>

typedef __bf16 bf16x8 __attribute__((ext_vector_type(8)));
typedef float f32x4 __attribute__((ext_vector_type(4)));
typedef unsigned short u16;

#define NROWS 4096
#define DIM 512
#define ZROWS 8192
#define DIMP 128     /* projected dims (Walsh coefficients 0..127) */
#define BM 128
#define BK 32
#define NKT 4        /* DIMP/BK */
#define NTILES 64    /* 8192/128 */
#define NBLOCKS 2080 /* 64*65/2 upper-triangular tile pairs */
#define CHUNK (NBLOCKS / 8)
#define THR 80.0f    /* certify-skip: d_proj>=80 => d_true>=~77 => term<e^-38 */

// ---------------- kernel 1: row norms (f32) + 128-dim Walsh projection -----------
// FWHT over 512 elems: lane l holds contiguous elems [8l,8l+8). 3 in-lane stages +
// 6 shfl_xor stages = exact Sylvester-order WHT. Coefficients p=8l+j; rows of the
// Hadamard matrix /sqrt(512) are exactly orthonormal, so for the subset p<128:
//   sum_p (h_p.(x-y))^2 / 512  <=  ||x-y||^2   (Parseval lower bound).
__global__ __launch_bounds__(256) void prep_kernel(const float* __restrict__ lbl,
                                                   const float* __restrict__ pred,
                                                   u16* __restrict__ Q,
                                                   float* __restrict__ xnorm,
                                                   float* __restrict__ pnorm) {
    const int w = threadIdx.x >> 6;
    const int l = threadIdx.x & 63;
    const int row = blockIdx.x * 4 + w;
    const float* src = (row < NROWS) ? (lbl + (size_t)row * DIM)
                                     : (pred + (size_t)(row - NROWS) * DIM);
    const float4 v0 = *(const float4*)(src + l * 8);
    const float4 v1 = *(const float4*)(src + l * 8 + 4);
    float h[8] = {v0.x, v0.y, v0.z, v0.w, v1.x, v1.y, v1.z, v1.w};

    float nrm = 0.f;  // exact f32 norm of the ORIGINAL row (for the exact fallback)
#pragma unroll
    for (int j = 0; j < 8; ++j) nrm += h[j] * h[j];
#pragma unroll
    for (int off = 32; off; off >>= 1) nrm += __shfl_xor(nrm, off);
    if (l == 0) xnorm[row] = nrm;

    // FWHT, in-lane stages (len 1,2,4)
#define BFLY(a, b) { float t = h[a]; h[a] = t + h[b]; h[b] = t - h[b]; }
    BFLY(0, 1) BFLY(2, 3) BFLY(4, 5) BFLY(6, 7)
    BFLY(0, 2) BFLY(1, 3) BFLY(4, 6) BFLY(5, 7)
    BFLY(0, 4) BFLY(1, 5) BFLY(2, 6) BFLY(3, 7)
#undef BFLY
    // cross-lane stages (len 8..256): position 8l+j pairs with 8(l^m)+j
#pragma unroll
    for (int m = 1; m <= 32; m <<= 1) {
#pragma unroll
        for (int j = 0; j < 8; ++j) {
            float p = __shfl_xor(h[j], m);
            h[j] = (l & m) ? (p - h[j]) : (h[j] + p);
        }
    }
    // quantize q = h / sqrt(512) to bf16 (RNE); pnorm from the bf16-rounded values
    float s = 0.f;
    uint32_t pk[4];
#pragma unroll
    for (int jj = 0; jj < 4; ++jj) {
        uint32_t b0 = __float_as_uint(h[2 * jj] * 0.04419417382f);
        uint32_t b1 = __float_as_uint(h[2 * jj + 1] * 0.04419417382f);
        uint32_t r0 = (b0 + 0x7fffu + ((b0 >> 16) & 1u)) >> 16;
        uint32_t r1 = (b1 + 0x7fffu + ((b1 >> 16) & 1u)) >> 16;
        pk[jj] = r0 | (r1 << 16);
        float fb0 = __uint_as_float(r0 << 16);
        float fb1 = __uint_as_float(r1 << 16);
        s += fb0 * fb0 + fb1 * fb1;
    }
    if (l < 16) *(uint4*)(Q + (size_t)row * DIMP + l * 8) = make_uint4(pk[0], pk[1], pk[2], pk[3]);
    s = (l < 16) ? s : 0.f;
#pragma unroll
    for (int off = 32; off; off >>= 1) s += __shfl_xor(s, off);
    if (l == 0) pnorm[row] = s;
}

// ---------------- exact fallback: f32 dot on ORIGINAL inputs ----------------------
__device__ __noinline__ float exact_term(const float* __restrict__ lbl,
                                         const float* __restrict__ pred,
                                         const float* __restrict__ xnorm,
                                         int i, int j) {
    const float* ri = (i < NROWS) ? (lbl + (size_t)i * DIM) : (pred + (size_t)(i - NROWS) * DIM);
    const float* rj = (j < NROWS) ? (lbl + (size_t)j * DIM) : (pred + (size_t)(j - NROWS) * DIM);
    float dot = 0.f;
#pragma unroll 1
    for (int k = 0; k < DIM; k += 4) {
        float4 a = *(const float4*)(ri + k);
        float4 b = *(const float4*)(rj + k);
        dot += a.x * b.x + a.y * b.y + a.z * b.z + a.w * b.w;
    }
    float dt = xnorm[i] + xnorm[j] - 2.f * dot;
    return exp2f(-0.72134752f * dt);
}

// ---------------- kernel 2: K=128 projected GEMM filter + exact fallback ----------
// Round-3 skeleton (proven): 2-phase prefetch, dbuf LDS 32 KiB, both-sides swizzle.
// Epilogue: certify d_true >= d_proj >= THR => skip (term provably < e^-38);
// else exact f32 recompute (includes the 8192 true-diagonal pairs).
__global__ __launch_bounds__(256) void mmd_filter_kernel(const u16* __restrict__ Q,
                                                         const float* __restrict__ pnorm,
                                                         const float* __restrict__ lbl,
                                                         const float* __restrict__ pred,
                                                         const float* __restrict__ xnorm,
                                                         float* __restrict__ partials) {
    __shared__ u16 lds[2][2][BM * BK];  // [dbuf][A/B][128*32]

    const int bid = (int)blockIdx.x;
    const int sbid = (bid & 7) * CHUNK + (bid >> 3);  // XCD-contiguous ranges
    int bm = 0, rem = sbid;
    while (rem >= (NTILES - bm)) { rem -= (NTILES - bm); ++bm; }
    const int bn = bm + rem;
    const bool diag = (bm == bn);

    const int tid = threadIdx.x;
    const int w = tid >> 6;
    const int l = tid & 63;
    const int warpM = w >> 1, warpN = w & 1;

    const char* qbytes = (const char*)Q;
    const size_t rowA0 = (size_t)bm * BM;
    const size_t rowB0 = (size_t)bn * BM;

    f32x4 acc[4][4];
#pragma unroll
    for (int m = 0; m < 4; ++m)
#pragma unroll
        for (int n = 0; n < 4; ++n) acc[m][n] = (f32x4){0.f, 0.f, 0.f, 0.f};

    auto STAGE = [&](int b, int kt) {
#pragma unroll
        for (int it = 0; it < 2; ++it) {
            const int r = it * 64 + w * 16 + (l >> 2);       // LDS row
            const int cb = (l & 3) * 16;                     // 16B slot
            const int csrc = cb ^ ((r & 3) << 4);            // pre-swizzled source slot
            const char* gA = qbytes + (rowA0 + r) * (DIMP * 2) + kt * 64 + csrc;
            char* lA = (char*)&lds[b][0][0] + it * 4096 + w * 1024 + l * 16;
            __builtin_amdgcn_global_load_lds((const __attribute__((address_space(1))) void*)gA,
                                             (__attribute__((address_space(3))) void*)lA, 16, 0, 0);
            if (!diag) {
                const char* gB = qbytes + (rowB0 + r) * (DIMP * 2) + kt * 64 + csrc;
                char* lB = (char*)&lds[b][1][0] + it * 4096 + w * 1024 + l * 16;
                __builtin_amdgcn_global_load_lds((const __attribute__((address_space(1))) void*)gB,
                                                 (__attribute__((address_space(3))) void*)lB, 16, 0, 0);
            }
        }
    };

    const int klane = ((l >> 4) * 16) ^ ((l & 3) << 4);  // read-side swizzle
    auto COMPUTE = [&](int b) {
        const char* abase = (const char*)&lds[b][0][0];
        const char* bbase = diag ? abase : (const char*)&lds[b][1][0];
        bf16x8 af[4], bg[4];
#pragma unroll
        for (int m = 0; m < 4; ++m) {
            const int rr = warpM * 64 + m * 16 + (l & 15);
            af[m] = *(const bf16x8*)(abase + rr * 64 + klane);
        }
#pragma unroll
        for (int n = 0; n < 4; ++n) {
            const int rr = warpN * 64 + n * 16 + (l & 15);
            bg[n] = *(const bf16x8*)(bbase + rr * 64 + klane);
        }
#pragma unroll
        for (int m = 0; m < 4; ++m)
#pragma unroll
            for (int n = 0; n < 4; ++n)
                acc[m][n] = __builtin_amdgcn_mfma_f32_16x16x32_bf16(af[m], bg[n], acc[m][n], 0, 0, 0);
    };

    STAGE(0, 0);
    __syncthreads();
    for (int kt = 0; kt < NKT; kt += 2) {
        STAGE(1, kt + 1);
        COMPUTE(0);
        __syncthreads();
        if (kt + 2 < NKT) STAGE(0, kt + 2);
        COMPUTE(1);
        __syncthreads();
    }

    // ---- epilogue: d_proj = pi + pj - 2*qi.qj ; certify-skip or exact fallback ---
    const int baseI = (int)rowA0 + warpM * 64;
    const int baseJ = (int)rowB0 + warpN * 64;
    float4 pi4[4];
    float pj[4];
#pragma unroll
    for (int m = 0; m < 4; ++m)
        pi4[m] = *(const float4*)(pnorm + baseI + m * 16 + (l >> 4) * 4);
#pragma unroll
    for (int n = 0; n < 4; ++n) pj[n] = pnorm[baseJ + n * 16 + (l & 15)];

    float local = 0.f;
#pragma unroll
    for (int m = 0; m < 4; ++m)
#pragma unroll
        for (int n = 0; n < 4; ++n) {
            float d0 = (pi4[m].x + pj[n]) - 2.f * acc[m][n][0];
            float d1 = (pi4[m].y + pj[n]) - 2.f * acc[m][n][1];
            float d2 = (pi4[m].z + pj[n]) - 2.f * acc[m][n][2];
            float d3 = (pi4[m].w + pj[n]) - 2.f * acc[m][n][3];
            float dmin = fminf(fminf(d0, d1), fminf(d2, d3));
            if (dmin < THR) {  // rare: only near-pairs (incl. true diagonal)
                const int i0 = baseI + m * 16 + (l >> 4) * 4;
                const int j = baseJ + n * 16 + (l & 15);
                if (d0 < THR) local += exact_term(lbl, pred, xnorm, i0 + 0, j);
                if (d1 < THR) local += exact_term(lbl, pred, xnorm, i0 + 1, j);
                if (d2 < THR) local += exact_term(lbl, pred, xnorm, i0 + 2, j);
                if (d3 < THR) local += exact_term(lbl, pred, xnorm, i0 + 3, j);
            }
        }
    const float sgn = ((bm < NROWS / BM) == (bn < NROWS / BM)) ? 1.f : -1.f;
    local *= sgn * (diag ? 1.f : 2.f);
#pragma unroll
    for (int off = 32; off; off >>= 1) local += __shfl_xor(local, off);
    float* red = (float*)&lds[0][0][0];  // reuse LDS post-barrier
    if (l == 0) red[w] = local;
    __syncthreads();
    if (tid == 0) partials[sbid] = red[0] + red[1] + red[2] + red[3];
}

// ---------------- kernel 3: deterministic final reduce ---------------------------
__global__ __launch_bounds__(256) void reduce_kernel(const float* __restrict__ partials,
                                                     float* __restrict__ out, int n) {
    __shared__ float red[4];
    float s = 0.f;
    for (int i = threadIdx.x; i < n; i += 256) s += partials[i];
#pragma unroll
    for (int off = 32; off; off >>= 1) s += __shfl_xor(s, off);
    if ((threadIdx.x & 63) == 0) red[threadIdx.x >> 6] = s;
    __syncthreads();
    if (threadIdx.x == 0)
        out[0] = (red[0] + red[1] + red[2] + red[3]) * (1.f / 16777216.f);  // / 4096^2
}

extern "C" void kernel_launch(void* const* d_in, const int* in_sizes, int n_in,
                              void* d_out, int out_size, void* d_ws, size_t ws_size,
                              hipStream_t stream) {
    const float* lbl = (const float*)d_in[0];
    const float* pred = (const float*)d_in[1];
    u16* Q = (u16*)d_ws;                                              // 2 MiB
    float* xnorm = (float*)((char*)d_ws + (size_t)ZROWS * DIMP * 2);  // 32 KiB
    float* pnorm = xnorm + ZROWS;                                     // 32 KiB
    float* partials = pnorm + ZROWS;

    prep_kernel<<<ZROWS / 4, 256, 0, stream>>>(lbl, pred, Q, xnorm, pnorm);
    mmd_filter_kernel<<<NBLOCKS, 256, 0, stream>>>(Q, pnorm, lbl, pred, xnorm, partials);
    reduce_kernel<<<1, 256, 0, stream>>>(partials, (float*)d_out, NBLOCKS);
}

// Round 6
// 48.254 us; speedup vs baseline: 7.7094x; 7.7094x over previous
//
#include <hip/hip_runtime.h>
#include <cstdint>

typedef __bf16 bf16x8 __attribute__((ext_vector_type(8)));
typedef float f32x4 __attribute__((ext_vector_type(4)));
typedef unsigned short u16;

#define NROWS 4096
#define DIM 512
#define ZROWS 8192
#define DIMP 128     /* projected dims (Walsh coefficients 0..127) */
#define BM 128
#define BK 32
#define NKT 4        /* DIMP/BK */
#define NTILES 64    /* 8192/128 */
#define NBLOCKS 2080 /* 64*65/2 upper-triangular tile pairs */
#define CHUNK (NBLOCKS / 8)
#define THR 80.0f    /* certify-skip: d_proj>=80 => d_true>=~79 => sum < 1e-9 */

// ---------------- kernel 1: row norms (f32) + 128-dim Walsh projection -----------
// FWHT over 512 elems: lane l holds contiguous elems [8l,8l+8). 3 in-lane stages +
// 6 shfl_xor stages = exact Sylvester-order WHT. Rows of Hadamard/sqrt(512) are
// exactly orthonormal => for the 128-subset: d_proj <= d_true (Parseval).
__global__ __launch_bounds__(256) void prep_kernel(const float* __restrict__ lbl,
                                                   const float* __restrict__ pred,
                                                   u16* __restrict__ Q,
                                                   float* __restrict__ xnorm,
                                                   float* __restrict__ pnorm) {
    const int w = threadIdx.x >> 6;
    const int l = threadIdx.x & 63;
    const int row = blockIdx.x * 4 + w;
    const float* src = (row < NROWS) ? (lbl + (size_t)row * DIM)
                                     : (pred + (size_t)(row - NROWS) * DIM);
    const float4 v0 = *(const float4*)(src + l * 8);
    const float4 v1 = *(const float4*)(src + l * 8 + 4);
    float h[8] = {v0.x, v0.y, v0.z, v0.w, v1.x, v1.y, v1.z, v1.w};

    float nrm = 0.f;  // exact f32 norm of the ORIGINAL row (for the exact fallback)
#pragma unroll
    for (int j = 0; j < 8; ++j) nrm += h[j] * h[j];
#pragma unroll
    for (int off = 32; off; off >>= 1) nrm += __shfl_xor(nrm, off);
    if (l == 0) xnorm[row] = nrm;

    // FWHT, in-lane stages (len 1,2,4)
#define BFLY(a, b) { float t = h[a]; h[a] = t + h[b]; h[b] = t - h[b]; }
    BFLY(0, 1) BFLY(2, 3) BFLY(4, 5) BFLY(6, 7)
    BFLY(0, 2) BFLY(1, 3) BFLY(4, 6) BFLY(5, 7)
    BFLY(0, 4) BFLY(1, 5) BFLY(2, 6) BFLY(3, 7)
#undef BFLY
    // cross-lane stages (len 8..256): position 8l+j pairs with 8(l^m)+j
#pragma unroll
    for (int m = 1; m <= 32; m <<= 1) {
#pragma unroll
        for (int j = 0; j < 8; ++j) {
            float p = __shfl_xor(h[j], m);
            h[j] = (l & m) ? (p - h[j]) : (h[j] + p);
        }
    }
    // quantize q = h / sqrt(512) to bf16 (RNE); pnorm from the bf16-rounded values
    float s = 0.f;
    uint32_t pk[4];
#pragma unroll
    for (int jj = 0; jj < 4; ++jj) {
        uint32_t b0 = __float_as_uint(h[2 * jj] * 0.04419417382f);
        uint32_t b1 = __float_as_uint(h[2 * jj + 1] * 0.04419417382f);
        uint32_t r0 = (b0 + 0x7fffu + ((b0 >> 16) & 1u)) >> 16;
        uint32_t r1 = (b1 + 0x7fffu + ((b1 >> 16) & 1u)) >> 16;
        pk[jj] = r0 | (r1 << 16);
        float fb0 = __uint_as_float(r0 << 16);
        float fb1 = __uint_as_float(r1 << 16);
        s += fb0 * fb0 + fb1 * fb1;
    }
    if (l < 16) *(uint4*)(Q + (size_t)row * DIMP + l * 8) = make_uint4(pk[0], pk[1], pk[2], pk[3]);
    s = (l < 16) ? s : 0.f;
#pragma unroll
    for (int off = 32; off; off >>= 1) s += __shfl_xor(s, off);
    if (l == 0) pnorm[row] = s;
}

// ---------------- kernel 2: K=128 projected GEMM filter + cooperative fallback ---
// Round-3 skeleton: 2-phase prefetch, dbuf LDS 32 KiB, both-sides swizzle.
// Epilogue: d_proj >= THR => provably negligible, skip. i==j => exact 1, handled
// as a constant in the reduce. Residual near-pairs (≈0 expected): whole-wave
// cooperative exact f32 dot (coalesced, 8 elems/lane, shuffle reduce).
__global__ __launch_bounds__(256) void mmd_filter_kernel(const u16* __restrict__ Q,
                                                         const float* __restrict__ pnorm,
                                                         const float* __restrict__ lbl,
                                                         const float* __restrict__ pred,
                                                         const float* __restrict__ xnorm,
                                                         float* __restrict__ partials) {
    __shared__ u16 lds[2][2][BM * BK];  // [dbuf][A/B][128*32]

    const int bid = (int)blockIdx.x;
    const int sbid = (bid & 7) * CHUNK + (bid >> 3);  // XCD-contiguous ranges
    int bm = 0, rem = sbid;
    while (rem >= (NTILES - bm)) { rem -= (NTILES - bm); ++bm; }
    const int bn = bm + rem;
    const bool diag = (bm == bn);

    const int tid = threadIdx.x;
    const int w = tid >> 6;
    const int l = tid & 63;
    const int warpM = w >> 1, warpN = w & 1;

    const char* qbytes = (const char*)Q;
    const size_t rowA0 = (size_t)bm * BM;
    const size_t rowB0 = (size_t)bn * BM;

    f32x4 acc[4][4];
#pragma unroll
    for (int m = 0; m < 4; ++m)
#pragma unroll
        for (int n = 0; n < 4; ++n) acc[m][n] = (f32x4){0.f, 0.f, 0.f, 0.f};

    auto STAGE = [&](int b, int kt) {
#pragma unroll
        for (int it = 0; it < 2; ++it) {
            const int r = it * 64 + w * 16 + (l >> 2);       // LDS row
            const int cb = (l & 3) * 16;                     // 16B slot
            const int csrc = cb ^ ((r & 3) << 4);            // pre-swizzled source slot
            const char* gA = qbytes + (rowA0 + r) * (DIMP * 2) + kt * 64 + csrc;
            char* lA = (char*)&lds[b][0][0] + it * 4096 + w * 1024 + l * 16;
            __builtin_amdgcn_global_load_lds((const __attribute__((address_space(1))) void*)gA,
                                             (__attribute__((address_space(3))) void*)lA, 16, 0, 0);
            if (!diag) {
                const char* gB = qbytes + (rowB0 + r) * (DIMP * 2) + kt * 64 + csrc;
                char* lB = (char*)&lds[b][1][0] + it * 4096 + w * 1024 + l * 16;
                __builtin_amdgcn_global_load_lds((const __attribute__((address_space(1))) void*)gB,
                                                 (__attribute__((address_space(3))) void*)lB, 16, 0, 0);
            }
        }
    };

    const int klane = ((l >> 4) * 16) ^ ((l & 3) << 4);  // read-side swizzle
    auto COMPUTE = [&](int b) {
        const char* abase = (const char*)&lds[b][0][0];
        const char* bbase = diag ? abase : (const char*)&lds[b][1][0];
        bf16x8 af[4], bg[4];
#pragma unroll
        for (int m = 0; m < 4; ++m) {
            const int rr = warpM * 64 + m * 16 + (l & 15);
            af[m] = *(const bf16x8*)(abase + rr * 64 + klane);
        }
#pragma unroll
        for (int n = 0; n < 4; ++n) {
            const int rr = warpN * 64 + n * 16 + (l & 15);
            bg[n] = *(const bf16x8*)(bbase + rr * 64 + klane);
        }
#pragma unroll
        for (int m = 0; m < 4; ++m)
#pragma unroll
            for (int n = 0; n < 4; ++n)
                acc[m][n] = __builtin_amdgcn_mfma_f32_16x16x32_bf16(af[m], bg[n], acc[m][n], 0, 0, 0);
    };

    STAGE(0, 0);
    __syncthreads();
    for (int kt = 0; kt < NKT; kt += 2) {
        STAGE(1, kt + 1);
        COMPUTE(0);
        __syncthreads();
        if (kt + 2 < NKT) STAGE(0, kt + 2);
        COMPUTE(1);
        __syncthreads();
    }

    // ---- epilogue ----------------------------------------------------------------
    const int baseI = (int)rowA0 + warpM * 64;
    const int baseJ = (int)rowB0 + warpN * 64;
    float4 pi4[4];
    float pj[4];
#pragma unroll
    for (int m = 0; m < 4; ++m)
        pi4[m] = *(const float4*)(pnorm + baseI + m * 16 + (l >> 4) * 4);
#pragma unroll
    for (int n = 0; n < 4; ++n) pj[n] = pnorm[baseJ + n * 16 + (l & 15)];

    float local = 0.f;
#pragma unroll
    for (int m = 0; m < 4; ++m)
#pragma unroll
        for (int n = 0; n < 4; ++n) {
            float d[4];
            d[0] = (pi4[m].x + pj[n]) - 2.f * acc[m][n][0];
            d[1] = (pi4[m].y + pj[n]) - 2.f * acc[m][n][1];
            d[2] = (pi4[m].z + pj[n]) - 2.f * acc[m][n][2];
            d[3] = (pi4[m].w + pj[n]) - 2.f * acc[m][n][3];
            const int i0 = baseI + m * 16 + (l >> 4) * 4;
            const int j = baseJ + n * 16 + (l & 15);
#pragma unroll
            for (int r = 0; r < 4; ++r) {
                // i==j is exp(0)=1 exactly — added as a constant in the reduce
                unsigned long long bal = __ballot((d[r] < THR) && (i0 + r != j));
                while (bal) {  // ≈never taken; wave-cooperative exact f32 term
                    const int src = __ffsll((long long)bal) - 1;
                    bal &= bal - 1;
                    const int ii = __shfl(i0 + r, src);
                    const int jj = __shfl(j, src);
                    const float* ri = (ii < NROWS) ? lbl + (size_t)ii * DIM
                                                   : pred + (size_t)(ii - NROWS) * DIM;
                    const float* rj = (jj < NROWS) ? lbl + (size_t)jj * DIM
                                                   : pred + (size_t)(jj - NROWS) * DIM;
                    const float4 a0 = *(const float4*)(ri + l * 8);
                    const float4 a1 = *(const float4*)(ri + l * 8 + 4);
                    const float4 c0 = *(const float4*)(rj + l * 8);
                    const float4 c1 = *(const float4*)(rj + l * 8 + 4);
                    float p = a0.x * c0.x + a0.y * c0.y + a0.z * c0.z + a0.w * c0.w +
                              a1.x * c1.x + a1.y * c1.y + a1.z * c1.z + a1.w * c1.w;
#pragma unroll
                    for (int off = 32; off; off >>= 1) p += __shfl_xor(p, off);
                    if (l == src) {
                        float dt = xnorm[ii] + xnorm[jj] - 2.f * p;
                        local += exp2f(-0.72134752f * dt);
                    }
                }
            }
        }
    const float sgn = ((bm < NROWS / BM) == (bn < NROWS / BM)) ? 1.f : -1.f;
    local *= sgn * (diag ? 1.f : 2.f);
#pragma unroll
    for (int off = 32; off; off >>= 1) local += __shfl_xor(local, off);
    float* red = (float*)&lds[0][0][0];  // reuse LDS post-barrier
    if (l == 0) red[w] = local;
    __syncthreads();
    if (tid == 0) partials[sbid] = red[0] + red[1] + red[2] + red[3];
}

// ---------------- kernel 3: deterministic final reduce ---------------------------
__global__ __launch_bounds__(256) void reduce_kernel(const float* __restrict__ partials,
                                                     float* __restrict__ out, int n) {
    __shared__ float red[4];
    float s = 0.f;
    for (int i = threadIdx.x; i < n; i += 256) s += partials[i];
#pragma unroll
    for (int off = 32; off; off >>= 1) s += __shfl_xor(s, off);
    if ((threadIdx.x & 63) == 0) red[threadIdx.x >> 6] = s;
    __syncthreads();
    if (threadIdx.x == 0)  // + 8192 = the Z-diagonal (exp(0)=1, sign +1, exact)
        out[0] = (red[0] + red[1] + red[2] + red[3] + 8192.f) * (1.f / 16777216.f);
}

extern "C" void kernel_launch(void* const* d_in, const int* in_sizes, int n_in,
                              void* d_out, int out_size, void* d_ws, size_t ws_size,
                              hipStream_t stream) {
    const float* lbl = (const float*)d_in[0];
    const float* pred = (const float*)d_in[1];
    u16* Q = (u16*)d_ws;                                              // 2 MiB
    float* xnorm = (float*)((char*)d_ws + (size_t)ZROWS * DIMP * 2);  // 32 KiB
    float* pnorm = xnorm + ZROWS;                                     // 32 KiB
    float* partials = pnorm + ZROWS;

    prep_kernel<<<ZROWS / 4, 256, 0, stream>>>(lbl, pred, Q, xnorm, pnorm);
    mmd_filter_kernel<<<NBLOCKS, 256, 0, stream>>>(Q, pnorm, lbl, pred, xnorm, partials);
    reduce_kernel<<<1, 256, 0, stream>>>(partials, (float*)d_out, NBLOCKS);
}